// Round 1
// baseline (338.434 us; speedup 1.0000x reference)
//
#include <hip/hip_runtime.h>

typedef __bf16 bf16x8 __attribute__((ext_vector_type(8)));
typedef float f32x4 __attribute__((ext_vector_type(4)));

namespace {
constexpr int Bn = 2, Cn = 64, hn = 96, wn = 96, Hn = 384, Wn = 384;
constexpr int CIN = 266, KP = 288;          // K of layer1 padded to 9*32
constexpr int TM = 64;                      // pixels per workgroup tile
constexpr int SP = 296;                     // Abuf row stride (bf16) -> 592B, bank-spread
constexpr int WROW = 40;                    // Wtile row stride (bf16) -> 80B, bank-spread
constexpr int W00_E = 256 * KP;             // 73728 bf16 elems
constexpr int W1_E  = 256 * 256;            // 65536
constexpr int W2_E  = 16 * 256;             // 4096 (rows 3..15 zero)
constexpr int SC_OFF_BYTES = (W00_E + W1_E + W2_E) * 2;  // 286720
}

// ---------------- prep: weights fp32 -> bf16 (padded layouts) ----------------
__global__ void prep_weights(const float* __restrict__ w00, const float* __restrict__ w1,
                             const float* __restrict__ w2, __bf16* __restrict__ wb)
{
    int idx = blockIdx.x * 256 + threadIdx.x;
    if (idx < W00_E) {
        int n = idx / KP, k = idx % KP;
        wb[idx] = (k < CIN) ? (__bf16)w00[n * CIN + k] : (__bf16)0.f;
    } else if (idx < W00_E + W1_E) {
        wb[idx] = (__bf16)w1[idx - W00_E];
    } else if (idx < W00_E + W1_E + W2_E) {
        int j = idx - (W00_E + W1_E);
        int n = j >> 8, k = j & 255;
        wb[idx] = (n < 3) ? (__bf16)w2[n * 256 + k] : (__bf16)0.f;
    }
}

// ---------------- prep: shortcut MLP on LR grid (fp32) ----------------
__global__ void prep_sc(const float* __restrict__ feat, const float* __restrict__ ws1,
                        const float* __restrict__ bs1, const float* __restrict__ ws2,
                        const float* __restrict__ bs2, float* __restrict__ sc)
{
    const int t = blockIdx.x * 256 + threadIdx.x;
    if (t >= Bn * hn * wn) return;
    const int b = t / (hn * wn);
    const int yx = t % (hn * wn);
    const float* fp = feat + b * Cn * hn * wn + yx;
    float f[Cn];
#pragma unroll
    for (int c = 0; c < Cn; c++) f[c] = fp[c * hn * wn];
    float o0 = bs2[0], o1 = bs2[1], o2 = bs2[2];
#pragma unroll 1
    for (int co = 0; co < Cn; co++) {
        float v = bs1[co];
        const float* wr = ws1 + co * Cn;
#pragma unroll
        for (int ci = 0; ci < Cn; ci++) v = fmaf(wr[ci], f[ci], v);
        v = fmaxf(v, 0.f);
        o0 = fmaf(ws2[co], v, o0);
        o1 = fmaf(ws2[Cn + co], v, o1);
        o2 = fmaf(ws2[2 * Cn + co], v, o2);
    }
    sc[(b * 3 + 0) * hn * wn + yx] = o0;
    sc[(b * 3 + 1) * hn * wn + yx] = o1;
    sc[(b * 3 + 2) * hn * wn + yx] = o2;
}

// ---------------- fused main kernel ----------------
// Per k-slab: stage 32xK weight slab to LDS (all 256 rows, 64B each), then
// each wave: 4 A-frags (its 4 m-blocks) x 4 B-frags (its 4 n-blocks) -> 16 MFMA.
template <int KSTEPS, int KROW>
__device__ __forceinline__ void gemm_stage(const __bf16* __restrict__ wsrc,
                                           __bf16 (&Abuf)[TM][SP],
                                           __bf16 (&Wtile)[256][WROW],
                                           f32x4 (&acc)[4][4],
                                           int t, int wv, int lane16, int quad)
{
#pragma unroll
    for (int k0 = 0; k0 < KSTEPS; k0++) {
        __syncthreads();   // prev iter's B-frag reads (and, at k0=0, Abuf writes) done
        {
            const bf16x8* src = (const bf16x8*)(wsrc + t * KROW + k0 * 32);
            bf16x8* dst = (bf16x8*)&Wtile[t][0];
            dst[0] = src[0]; dst[1] = src[1]; dst[2] = src[2]; dst[3] = src[3];
        }
        __syncthreads();
        bf16x8 af[4], bw[4];
#pragma unroll
        for (int m = 0; m < 4; m++)
            af[m] = *(const bf16x8*)&Abuf[m * 16 + lane16][k0 * 32 + quad * 8];
#pragma unroll
        for (int j = 0; j < 4; j++)
            bw[j] = *(const bf16x8*)&Wtile[(wv * 4 + j) * 16 + lane16][quad * 8];
#pragma unroll
        for (int m = 0; m < 4; m++)
#pragma unroll
            for (int j = 0; j < 4; j++)
                acc[m][j] = __builtin_amdgcn_mfma_f32_16x16x32_bf16(af[m], bw[j], acc[m][j], 0, 0, 0);
    }
}

__global__ __launch_bounds__(256, 2) void liif_main(
    const float* __restrict__ feat, const float* __restrict__ b00v,
    const float* __restrict__ b1v, const float* __restrict__ b2v,
    const __bf16* __restrict__ wb, const float* __restrict__ sc,
    float* __restrict__ out)
{
    __shared__ __align__(16) __bf16 Abuf[TM][SP];
    __shared__ __align__(16) __bf16 Wtile[256][WROW];

    const int t = threadIdx.x;
    const int wv = t >> 6;
    const int lane = t & 63;
    const int lane16 = lane & 15;
    const int quad = lane >> 4;

    const int wg = blockIdx.x;
    constexpr int TPR = Wn / TM;  // 6 tiles per HR row
    const int tx = wg % TPR;
    const int Y = (wg / TPR) % Hn;
    const int b = wg / (TPR * Hn);
    const int X0 = tx * TM;

    const float cy = -1.f + 1.f / Hn + (2.f / Hn) * (float)Y;

    // ---------- phase 1: build grid features [64 x 266] bf16 in Abuf ----------
    {
        const int p = lane;     // pixel in tile
        const int j = wv;       // this wave handles corner j's gather
        const int X = X0 + p;
        const float cx = -1.f + 1.f / Wn + (2.f / Wn) * (float)X;
        float rely[4], relx[4], area[4];
        int iyv[4], ixv[4];
#pragma unroll
        for (int c = 0; c < 4; c++) {
            const float vx = (c & 2) ? 1.f : -1.f;   // shift along height
            const float vy = (c & 1) ? 1.f : -1.f;   // shift along width
            float sy = fminf(fmaxf(cy + vx * (1.f / hn) + 1e-6f, -1.f + 1e-6f), 1.f - 1e-6f);
            float sx = fminf(fmaxf(cx + vy * (1.f / wn) + 1e-6f, -1.f + 1e-6f), 1.f - 1e-6f);
            float uy = ((sy + 1.f) * hn - 1.f) * 0.5f;
            float ux = ((sx + 1.f) * wn - 1.f) * 0.5f;
            int iy = min(max((int)rintf(uy), 0), hn - 1);   // round-half-even == jnp.round
            int ix = min(max((int)rintf(ux), 0), wn - 1);
            float oy = -1.f + 1.f / hn + (2.f / hn) * (float)iy;
            float ox = -1.f + 1.f / wn + (2.f / wn) * (float)ix;
            rely[c] = (cy - oy) * hn;
            relx[c] = (cx - ox) * wn;
            area[c] = fabsf(rely[c] * relx[c]) + 1e-9f;
            iyv[c] = iy; ixv[c] = ix;
        }
        const float tot = area[0] + area[1] + area[2] + area[3];
        const float wj = area[3 - j] / tot;   // LIIF area swap 0<->3, 1<->2

        if (j == 0) {  // channels 0..7: [rel_y0, rel_x0, ..., rel_y3, rel_x3]
            bf16x8 v;
#pragma unroll
            for (int c = 0; c < 4; c++) { v[2 * c] = (__bf16)rely[c]; v[2 * c + 1] = (__bf16)relx[c]; }
            *(bf16x8*)&Abuf[p][0] = v;
        }
        // channels 8+64j .. 8+64j+63: feat at (iy_j, ix_j) scaled by wj
        const float* fb = feat + ((b * Cn) * hn + iyv[j]) * wn + ixv[j];
#pragma unroll
        for (int c8 = 0; c8 < 8; c8++) {
            bf16x8 v;
#pragma unroll
            for (int cc = 0; cc < 8; cc++)
                v[cc] = (__bf16)(fb[(c8 * 8 + cc) * (hn * wn)] * wj);
            *(bf16x8*)&Abuf[p][8 + 64 * j + c8 * 8] = v;
        }
        if (j == 3) {  // channels 264,265 = rel_cell (0.5, 0.5); 266..287 zero pad
            bf16x8 z;
#pragma unroll
            for (int cc = 0; cc < 8; cc++) z[cc] = (__bf16)0.f;
            bf16x8 v = z;
            v[0] = (__bf16)0.5f; v[1] = (__bf16)0.5f;
            *(bf16x8*)&Abuf[p][264] = v;
            *(bf16x8*)&Abuf[p][272] = z;
            *(bf16x8*)&Abuf[p][280] = z;
        }
    }

    // ---------- layer 1: [64x288] @ [288x256] ----------
    f32x4 acc[4][4];
#pragma unroll
    for (int m = 0; m < 4; m++)
#pragma unroll
        for (int j = 0; j < 4; j++) acc[m][j] = (f32x4){0.f, 0.f, 0.f, 0.f};

    gemm_stage<KP / 32, KP>(wb, Abuf, Wtile, acc, t, wv, lane16, quad);

    __syncthreads();  // all A-frag readers done before overwriting Abuf with X
#pragma unroll
    for (int j = 0; j < 4; j++) {
        const int ch = (wv * 4 + j) * 16 + lane16;
        const float bias = b00v[ch];
#pragma unroll
        for (int m = 0; m < 4; m++)
#pragma unroll
            for (int r = 0; r < 4; r++)
                Abuf[m * 16 + quad * 4 + r][ch] = (__bf16)(acc[m][j][r] + bias);
    }

    // ---------- layer 2: gelu([64x256] @ [256x256]) ----------
#pragma unroll
    for (int m = 0; m < 4; m++)
#pragma unroll
        for (int j = 0; j < 4; j++) acc[m][j] = (f32x4){0.f, 0.f, 0.f, 0.f};

    gemm_stage<256 / 32, 256>(wb + W00_E, Abuf, Wtile, acc, t, wv, lane16, quad);

    __syncthreads();
#pragma unroll
    for (int j = 0; j < 4; j++) {
        const int ch = (wv * 4 + j) * 16 + lane16;
        const float bias = b1v[ch];
#pragma unroll
        for (int m = 0; m < 4; m++)
#pragma unroll
            for (int r = 0; r < 4; r++) {
                float v = acc[m][j][r] + bias;
                v = 0.5f * v * (1.f + erff(v * 0.70710678f));  // exact gelu
                Abuf[m * 16 + quad * 4 + r][ch] = (__bf16)v;
            }
    }
    __syncthreads();

    // ---------- layer 3: [64x256] @ [256x16(3 valid)], wave wv owns m-block wv ----------
    f32x4 acc3 = (f32x4){0.f, 0.f, 0.f, 0.f};
    const __bf16* w2b = wb + W00_E + W1_E;
#pragma unroll
    for (int k0 = 0; k0 < 8; k0++) {
        bf16x8 af = *(const bf16x8*)&Abuf[wv * 16 + lane16][k0 * 32 + quad * 8];
        bf16x8 bw = *(const bf16x8*)(w2b + lane16 * 256 + k0 * 32 + quad * 8);
        acc3 = __builtin_amdgcn_mfma_f32_16x16x32_bf16(af, bw, acc3, 0, 0, 0);
    }

    // ---------- epilogue: + b2 + bilinear(border) shortcut sample ----------
    const int n = lane16;
    if (n < 3) {
        const float uy = ((cy + 1.f) * hn - 1.f) * 0.5f;
        const float fy = floorf(uy);
        const float wy = uy - fy;
        const int y0i = min(max((int)fy, 0), hn - 1);
        const int y1i = min(max((int)fy + 1, 0), hn - 1);
        const float bias = b2v[n];
        const float* scb = sc + (b * 3 + n) * (hn * wn);
        float* ob = out + ((b * 3 + n) * Hn + Y) * Wn;
#pragma unroll
        for (int r = 0; r < 4; r++) {
            const int p = wv * 16 + quad * 4 + r;
            const int X = X0 + p;
            const float cx = -1.f + 1.f / Wn + (2.f / Wn) * (float)X;
            const float ux = ((cx + 1.f) * wn - 1.f) * 0.5f;
            const float fx = floorf(ux);
            const float wx = ux - fx;
            const int x0i = min(max((int)fx, 0), wn - 1);
            const int x1i = min(max((int)fx + 1, 0), wn - 1);
            const float s00 = scb[y0i * wn + x0i], s01 = scb[y0i * wn + x1i];
            const float s10 = scb[y1i * wn + x0i], s11 = scb[y1i * wn + x1i];
            const float samp = s00 * (1.f - wy) * (1.f - wx) + s01 * (1.f - wy) * wx
                             + s10 * wy * (1.f - wx) + s11 * wy * wx;
            ob[X] = acc3[r] + bias + samp;
        }
    }
}

extern "C" void kernel_launch(void* const* d_in, const int* in_sizes, int n_in,
                              void* d_out, int out_size, void* d_ws, size_t ws_size,
                              hipStream_t stream)
{
    const float* feat = (const float*)d_in[0];
    const float* w00  = (const float*)d_in[1];
    const float* b00  = (const float*)d_in[2];
    const float* w1   = (const float*)d_in[3];
    const float* b1   = (const float*)d_in[4];
    const float* w2   = (const float*)d_in[5];
    const float* b2   = (const float*)d_in[6];
    const float* ws1  = (const float*)d_in[7];
    const float* bs1  = (const float*)d_in[8];
    const float* ws2  = (const float*)d_in[9];
    const float* bs2  = (const float*)d_in[10];
    float* out = (float*)d_out;

    __bf16* wb = (__bf16*)d_ws;
    float* scbuf = (float*)((char*)d_ws + SC_OFF_BYTES);

    prep_weights<<<(W00_E + W1_E + W2_E + 255) / 256, 256, 0, stream>>>(w00, w1, w2, wb);
    prep_sc<<<(Bn * hn * wn + 255) / 256, 256, 0, stream>>>(feat, ws1, bs1, ws2, bs2, scbuf);
    liif_main<<<Bn * Hn * (Wn / TM), 256, 0, stream>>>(feat, b00, b1, b2, wb, scbuf, out);
}

// Round 2
// 228.171 us; speedup vs baseline: 1.4832x; 1.4832x over previous
//
#include <hip/hip_runtime.h>

typedef __bf16 bf16x8 __attribute__((ext_vector_type(8)));
typedef float f32x4 __attribute__((ext_vector_type(4)));

namespace {
constexpr int Bn = 2, Cn = 64, hn = 96, wn = 96, Hn = 384, Wn = 384;
constexpr int CIN = 266;
constexpr int TM = 64;                      // pixels per workgroup tile
constexpr int SP = 296;                     // Abuf row stride (bf16): 592B, bank-spread
// fragment-major weight layouts (built by prep_weights):
//   layer1: 9 ksteps x 16 nblocks x 64 lanes x 8 elems
//   layer2: 8 ksteps x 16 nblocks x 64 lanes x 8
//   layer3: 8 ksteps x  1 nblock  x 64 lanes x 8 (n<3 valid, rest zero)
constexpr int L1_FRAGS = 9 * 16 * 64;       // 9216
constexpr int L2_FRAGS = 8 * 16 * 64;       // 8192
constexpr int L3_FRAGS = 8 * 64;            // 512
constexpr int N_FRAGS = L1_FRAGS + L2_FRAGS + L3_FRAGS;   // 17920
constexpr int SC_OFF_BYTES = N_FRAGS * 16;  // 286720 bytes of bf16 frags
}

// ---------------- prep: weights fp32 -> bf16 fragment-major ----------------
// One thread per 16-byte fragment (8 bf16). B-frag element mapping for
// mfma_f32_16x16x32_bf16: lane l supplies B[n = l&15][k = (l>>4)*8 + j].
__global__ void prep_weights(const float* __restrict__ w00, const float* __restrict__ w1,
                             const float* __restrict__ w2, __bf16* __restrict__ wb)
{
    const int f = blockIdx.x * 256 + threadIdx.x;
    if (f >= N_FRAGS) return;
    bf16x8 v;
    if (f < L1_FRAGS) {
        const int k0 = f >> 10;             // /(16*64)
        const int nb = (f >> 6) & 15;
        const int l  = f & 63;
        const int n  = nb * 16 + (l & 15);
        const int kb = k0 * 32 + (l >> 4) * 8;
#pragma unroll
        for (int j = 0; j < 8; j++)
            v[j] = (kb + j < CIN) ? (__bf16)w00[n * CIN + kb + j] : (__bf16)0.f;
    } else if (f < L1_FRAGS + L2_FRAGS) {
        const int g = f - L1_FRAGS;
        const int k0 = g >> 10;
        const int nb = (g >> 6) & 15;
        const int l  = g & 63;
        const int n  = nb * 16 + (l & 15);
        const int kb = k0 * 32 + (l >> 4) * 8;
#pragma unroll
        for (int j = 0; j < 8; j++) v[j] = (__bf16)w1[n * 256 + kb + j];
    } else {
        const int g = f - (L1_FRAGS + L2_FRAGS);
        const int k0 = g >> 6;
        const int l  = g & 63;
        const int n  = l & 15;
        const int kb = k0 * 32 + (l >> 4) * 8;
#pragma unroll
        for (int j = 0; j < 8; j++)
            v[j] = (n < 3) ? (__bf16)w2[n * 256 + kb + j] : (__bf16)0.f;
    }
    *(bf16x8*)(wb + f * 8) = v;
}

// ---------------- prep: shortcut MLP on LR grid (fp32) ----------------
__global__ void prep_sc(const float* __restrict__ feat, const float* __restrict__ ws1,
                        const float* __restrict__ bs1, const float* __restrict__ ws2,
                        const float* __restrict__ bs2, float* __restrict__ sc)
{
    const int t = blockIdx.x * 256 + threadIdx.x;
    if (t >= Bn * hn * wn) return;
    const int b = t / (hn * wn);
    const int yx = t % (hn * wn);
    const float* fp = feat + b * Cn * hn * wn + yx;
    float f[Cn];
#pragma unroll
    for (int c = 0; c < Cn; c++) f[c] = fp[c * hn * wn];
    float o0 = bs2[0], o1 = bs2[1], o2 = bs2[2];
#pragma unroll 1
    for (int co = 0; co < Cn; co++) {
        float v = bs1[co];
        const float* wr = ws1 + co * Cn;
#pragma unroll
        for (int ci = 0; ci < Cn; ci++) v = fmaf(wr[ci], f[ci], v);
        v = fmaxf(v, 0.f);
        o0 = fmaf(ws2[co], v, o0);
        o1 = fmaf(ws2[Cn + co], v, o1);
        o2 = fmaf(ws2[2 * Cn + co], v, o2);
    }
    sc[(b * 3 + 0) * hn * wn + yx] = o0;
    sc[(b * 3 + 1) * hn * wn + yx] = o1;
    sc[(b * 3 + 2) * hn * wn + yx] = o2;
}

// ---------------- fused main kernel ----------------
// B-frags stream global->VGPR from fragment-major layout (L2-resident,
// fully coalesced, 2-deep register prefetch, NO barriers in the k-loop).
template <int KSTEPS>
__device__ __forceinline__ void gemm_fused(const bf16x8* __restrict__ wf,
                                           __bf16 (&Abuf)[TM][SP],
                                           f32x4 (&acc)[4][4],
                                           int wv, int lane, int lane16, int quad)
{
    const int nb0 = wv * 4;
    bf16x8 buf[2][4];
#pragma unroll
    for (int j = 0; j < 4; j++) buf[0][j] = wf[(nb0 + j) * 64 + lane];
#pragma unroll
    for (int j = 0; j < 4; j++) buf[1][j] = wf[(16 + nb0 + j) * 64 + lane];
#pragma unroll
    for (int k0 = 0; k0 < KSTEPS; k0++) {
        bf16x8 bw0 = buf[k0 & 1][0], bw1 = buf[k0 & 1][1];
        bf16x8 bw2 = buf[k0 & 1][2], bw3 = buf[k0 & 1][3];
        if (k0 + 2 < KSTEPS) {
#pragma unroll
            for (int j = 0; j < 4; j++)
                buf[k0 & 1][j] = wf[((k0 + 2) * 16 + nb0 + j) * 64 + lane];
        }
        bf16x8 af[4];
#pragma unroll
        for (int m = 0; m < 4; m++)
            af[m] = *(const bf16x8*)&Abuf[m * 16 + lane16][k0 * 32 + quad * 8];
#pragma unroll
        for (int m = 0; m < 4; m++) {
            acc[m][0] = __builtin_amdgcn_mfma_f32_16x16x32_bf16(af[m], bw0, acc[m][0], 0, 0, 0);
            acc[m][1] = __builtin_amdgcn_mfma_f32_16x16x32_bf16(af[m], bw1, acc[m][1], 0, 0, 0);
            acc[m][2] = __builtin_amdgcn_mfma_f32_16x16x32_bf16(af[m], bw2, acc[m][2], 0, 0, 0);
            acc[m][3] = __builtin_amdgcn_mfma_f32_16x16x32_bf16(af[m], bw3, acc[m][3], 0, 0, 0);
        }
    }
}

__global__ __launch_bounds__(256, 2) void liif_main(
    const float* __restrict__ feat, const float* __restrict__ b00v,
    const float* __restrict__ b1v, const float* __restrict__ b2v,
    const __bf16* __restrict__ wb, const float* __restrict__ sc,
    float* __restrict__ out)
{
    __shared__ __align__(16) __bf16 Abuf[TM][SP];

    const int t = threadIdx.x;
    const int wv = t >> 6;
    const int lane = t & 63;
    const int lane16 = lane & 15;
    const int quad = lane >> 4;

    const int wg = blockIdx.x;
    constexpr int TPR = Wn / TM;  // 6 tiles per HR row
    const int tx = wg % TPR;
    const int Y = (wg / TPR) % Hn;
    const int b = wg / (TPR * Hn);
    const int X0 = tx * TM;

    const float cy = -1.f + 1.f / Hn + (2.f / Hn) * (float)Y;

    // ---------- phase 1: build grid features [64 x 266] bf16 in Abuf ----------
    {
        const int p = lane;     // pixel in tile
        const int j = wv;       // this wave handles corner j's gather
        const int X = X0 + p;
        const float cx = -1.f + 1.f / Wn + (2.f / Wn) * (float)X;
        float rely[4], relx[4], area[4];
        int iyv[4], ixv[4];
#pragma unroll
        for (int c = 0; c < 4; c++) {
            const float vx = (c & 2) ? 1.f : -1.f;   // shift along height
            const float vy = (c & 1) ? 1.f : -1.f;   // shift along width
            float sy = fminf(fmaxf(cy + vx * (1.f / hn) + 1e-6f, -1.f + 1e-6f), 1.f - 1e-6f);
            float sx = fminf(fmaxf(cx + vy * (1.f / wn) + 1e-6f, -1.f + 1e-6f), 1.f - 1e-6f);
            float uy = ((sy + 1.f) * hn - 1.f) * 0.5f;
            float ux = ((sx + 1.f) * wn - 1.f) * 0.5f;
            int iy = min(max((int)rintf(uy), 0), hn - 1);   // round-half-even == jnp.round
            int ix = min(max((int)rintf(ux), 0), wn - 1);
            float oy = -1.f + 1.f / hn + (2.f / hn) * (float)iy;
            float ox = -1.f + 1.f / wn + (2.f / wn) * (float)ix;
            rely[c] = (cy - oy) * hn;
            relx[c] = (cx - ox) * wn;
            area[c] = fabsf(rely[c] * relx[c]) + 1e-9f;
            iyv[c] = iy; ixv[c] = ix;
        }
        const float tot = area[0] + area[1] + area[2] + area[3];
        const float wj = area[3 - j] / tot;   // LIIF area swap 0<->3, 1<->2

        if (j == 0) {  // channels 0..7: [rel_y0, rel_x0, ..., rel_y3, rel_x3]
            bf16x8 v;
#pragma unroll
            for (int c = 0; c < 4; c++) { v[2 * c] = (__bf16)rely[c]; v[2 * c + 1] = (__bf16)relx[c]; }
            *(bf16x8*)&Abuf[p][0] = v;
        }
        // channels 8+64j .. 8+64j+63: feat at (iy_j, ix_j) scaled by wj
        const float* fb = feat + ((b * Cn) * hn + iyv[j]) * wn + ixv[j];
#pragma unroll
        for (int c8 = 0; c8 < 8; c8++) {
            bf16x8 v;
#pragma unroll
            for (int cc = 0; cc < 8; cc++)
                v[cc] = (__bf16)(fb[(c8 * 8 + cc) * (hn * wn)] * wj);
            *(bf16x8*)&Abuf[p][8 + 64 * j + c8 * 8] = v;
        }
        if (j == 3) {  // channels 264,265 = rel_cell (0.5, 0.5); 266..287 zero pad
            bf16x8 z;
#pragma unroll
            for (int cc = 0; cc < 8; cc++) z[cc] = (__bf16)0.f;
            bf16x8 v = z;
            v[0] = (__bf16)0.5f; v[1] = (__bf16)0.5f;
            *(bf16x8*)&Abuf[p][264] = v;
            *(bf16x8*)&Abuf[p][272] = z;
            *(bf16x8*)&Abuf[p][280] = z;
        }
    }
    __syncthreads();

    // ---------- layer 1: [64x288] @ [288x256] ----------
    f32x4 acc[4][4];
#pragma unroll
    for (int m = 0; m < 4; m++)
#pragma unroll
        for (int j = 0; j < 4; j++) acc[m][j] = (f32x4){0.f, 0.f, 0.f, 0.f};

    gemm_fused<9>((const bf16x8*)wb, Abuf, acc, wv, lane, lane16, quad);

    __syncthreads();  // all A-frag readers done before overwriting Abuf with X
#pragma unroll
    for (int j = 0; j < 4; j++) {
        const int ch = (wv * 4 + j) * 16 + lane16;
        const float bias = b00v[ch];
#pragma unroll
        for (int m = 0; m < 4; m++)
#pragma unroll
            for (int r = 0; r < 4; r++)
                Abuf[m * 16 + quad * 4 + r][ch] = (__bf16)(acc[m][j][r] + bias);
    }
    __syncthreads();

    // ---------- layer 2: gelu([64x256] @ [256x256]) ----------
#pragma unroll
    for (int m = 0; m < 4; m++)
#pragma unroll
        for (int j = 0; j < 4; j++) acc[m][j] = (f32x4){0.f, 0.f, 0.f, 0.f};

    gemm_fused<8>((const bf16x8*)wb + L1_FRAGS, Abuf, acc, wv, lane, lane16, quad);

    __syncthreads();
#pragma unroll
    for (int j = 0; j < 4; j++) {
        const int ch = (wv * 4 + j) * 16 + lane16;
        const float bias = b1v[ch];
#pragma unroll
        for (int m = 0; m < 4; m++)
#pragma unroll
            for (int r = 0; r < 4; r++) {
                float v = acc[m][j][r] + bias;
                v = 0.5f * v * (1.f + erff(v * 0.70710678f));  // exact gelu
                Abuf[m * 16 + quad * 4 + r][ch] = (__bf16)v;
            }
    }
    __syncthreads();

    // ---------- layer 3: [64x256] @ [256x16(3 valid)], wave wv owns m-block wv ----------
    f32x4 acc3 = (f32x4){0.f, 0.f, 0.f, 0.f};
    const bf16x8* w2f = (const bf16x8*)wb + (L1_FRAGS + L2_FRAGS);
    bf16x8 wbuf[2];
    wbuf[0] = w2f[lane];
    wbuf[1] = w2f[64 + lane];
#pragma unroll
    for (int k0 = 0; k0 < 8; k0++) {
        bf16x8 bw = wbuf[k0 & 1];
        if (k0 + 2 < 8) wbuf[k0 & 1] = w2f[(k0 + 2) * 64 + lane];
        bf16x8 af = *(const bf16x8*)&Abuf[wv * 16 + lane16][k0 * 32 + quad * 8];
        acc3 = __builtin_amdgcn_mfma_f32_16x16x32_bf16(af, bw, acc3, 0, 0, 0);
    }

    // ---------- epilogue: + b2 + bilinear(border) shortcut sample ----------
    const int n = lane16;
    if (n < 3) {
        const float uy = ((cy + 1.f) * hn - 1.f) * 0.5f;
        const float fy = floorf(uy);
        const float wy = uy - fy;
        const int y0i = min(max((int)fy, 0), hn - 1);
        const int y1i = min(max((int)fy + 1, 0), hn - 1);
        const float bias = b2v[n];
        const float* scb = sc + (b * 3 + n) * (hn * wn);
        float* ob = out + ((b * 3 + n) * Hn + Y) * Wn;
#pragma unroll
        for (int r = 0; r < 4; r++) {
            const int p = wv * 16 + quad * 4 + r;
            const int X = X0 + p;
            const float cx = -1.f + 1.f / Wn + (2.f / Wn) * (float)X;
            const float ux = ((cx + 1.f) * wn - 1.f) * 0.5f;
            const float fx = floorf(ux);
            const float wx = ux - fx;
            const int x0i = min(max((int)fx, 0), wn - 1);
            const int x1i = min(max((int)fx + 1, 0), wn - 1);
            const float s00 = scb[y0i * wn + x0i], s01 = scb[y0i * wn + x1i];
            const float s10 = scb[y1i * wn + x0i], s11 = scb[y1i * wn + x1i];
            const float samp = s00 * (1.f - wy) * (1.f - wx) + s01 * (1.f - wy) * wx
                             + s10 * wy * (1.f - wx) + s11 * wy * wx;
            ob[X] = acc3[r] + bias + samp;
        }
    }
}

extern "C" void kernel_launch(void* const* d_in, const int* in_sizes, int n_in,
                              void* d_out, int out_size, void* d_ws, size_t ws_size,
                              hipStream_t stream)
{
    const float* feat = (const float*)d_in[0];
    const float* w00  = (const float*)d_in[1];
    const float* b00  = (const float*)d_in[2];
    const float* w1   = (const float*)d_in[3];
    const float* b1   = (const float*)d_in[4];
    const float* w2   = (const float*)d_in[5];
    const float* b2   = (const float*)d_in[6];
    const float* ws1  = (const float*)d_in[7];
    const float* bs1  = (const float*)d_in[8];
    const float* ws2  = (const float*)d_in[9];
    const float* bs2  = (const float*)d_in[10];
    float* out = (float*)d_out;

    __bf16* wb = (__bf16*)d_ws;
    float* scbuf = (float*)((char*)d_ws + SC_OFF_BYTES);

    prep_weights<<<(N_FRAGS + 255) / 256, 256, 0, stream>>>(w00, w1, w2, wb);
    prep_sc<<<(Bn * hn * wn + 255) / 256, 256, 0, stream>>>(feat, ws1, bs1, ws2, bs2, scbuf);
    liif_main<<<Bn * Hn * (Wn / TM), 256, 0, stream>>>(feat, b00, b1, b2, wb, scbuf, out);
}

// Round 3
// 212.016 us; speedup vs baseline: 1.5963x; 1.0762x over previous
//
#include <hip/hip_runtime.h>

typedef __bf16 bf16x8 __attribute__((ext_vector_type(8)));
typedef __bf16 bf16x4 __attribute__((ext_vector_type(4)));
typedef float f32x4 __attribute__((ext_vector_type(4)));

namespace {
constexpr int Bn = 2, Cn = 64, hn = 96, wn = 96, Hn = 384, Wn = 384;
constexpr int CIN = 266;
constexpr int TM = 64;                      // pixels per workgroup tile
constexpr int SP = 296;                     // Abuf row stride (bf16): 592B, bank-spread
// fragment-major weight layouts (built by prep_weights). A-frag mapping for
// mfma_f32_16x16x32_bf16: lane l supplies A[m = l&15][k = (l>>4)*8 + j].
//   layer1: 9 ksteps x 16 mblocks x 64 lanes x 8 elems
//   layer2: 8 ksteps x 16 mblocks x 64 lanes x 8
//   layer3: 8 ksteps x  1 mblock  x 64 lanes x 8 (m<3 valid, rest zero)
constexpr int L1_FRAGS = 9 * 16 * 64;       // 9216
constexpr int L2_FRAGS = 8 * 16 * 64;       // 8192
constexpr int L3_FRAGS = 8 * 64;            // 512
constexpr int N_FRAGS = L1_FRAGS + L2_FRAGS + L3_FRAGS;   // 17920
constexpr int SC_OFF_BYTES = N_FRAGS * 16;                 // 286720
constexpr int B1EFF_OFF_BYTES = SC_OFF_BYTES + Bn * 3 * hn * wn * 4;  // +221184
}

// ---------------- prep: weights fp32 -> bf16 fragment-major + b1eff ----------------
__global__ void prep_weights(const float* __restrict__ w00, const float* __restrict__ w1,
                             const float* __restrict__ w2, const float* __restrict__ b00,
                             const float* __restrict__ b1,
                             __bf16* __restrict__ wb, float* __restrict__ b1eff)
{
    if (blockIdx.x == N_FRAGS / 256) {
        // b1eff[o] = b1[o] + sum_c w1[o][c] * (b00[c] + 0.5*(w00[c][264]+w00[c][265]))
        __shared__ float cb[256];
        const int o = threadIdx.x;
        cb[o] = b00[o] + 0.5f * (w00[o * CIN + 264] + w00[o * CIN + 265]);
        __syncthreads();
        float v = b1[o];
#pragma unroll 4
        for (int k = 0; k < 256; k++) v = fmaf(w1[o * 256 + k], cb[k], v);
        b1eff[o] = v;
        return;
    }
    const int f = blockIdx.x * 256 + threadIdx.x;
    bf16x8 v;
    if (f < L1_FRAGS) {
        const int k0 = f >> 10;             // /(16*64)
        const int mb = (f >> 6) & 15;
        const int l  = f & 63;
        const int m  = mb * 16 + (l & 15);
        const int kb = k0 * 32 + (l >> 4) * 8;
#pragma unroll
        for (int j = 0; j < 8; j++)
            v[j] = (kb + j < CIN) ? (__bf16)w00[m * CIN + kb + j] : (__bf16)0.f;
    } else if (f < L1_FRAGS + L2_FRAGS) {
        const int g = f - L1_FRAGS;
        const int k0 = g >> 10;
        const int mb = (g >> 6) & 15;
        const int l  = g & 63;
        const int m  = mb * 16 + (l & 15);
        const int kb = k0 * 32 + (l >> 4) * 8;
#pragma unroll
        for (int j = 0; j < 8; j++) v[j] = (__bf16)w1[m * 256 + kb + j];
    } else {
        const int g = f - (L1_FRAGS + L2_FRAGS);
        const int k0 = g >> 6;
        const int l  = g & 63;
        const int m  = l & 15;
        const int kb = k0 * 32 + (l >> 4) * 8;
#pragma unroll
        for (int j = 0; j < 8; j++)
            v[j] = (m < 3) ? (__bf16)w2[m * 256 + kb + j] : (__bf16)0.f;
    }
    *(bf16x8*)(wb + f * 8) = v;
}

// ---------------- prep: shortcut MLP on LR grid (fp32) ----------------
__global__ void prep_sc(const float* __restrict__ feat, const float* __restrict__ ws1,
                        const float* __restrict__ bs1, const float* __restrict__ ws2,
                        const float* __restrict__ bs2, float* __restrict__ sc)
{
    const int t = blockIdx.x * 256 + threadIdx.x;
    if (t >= Bn * hn * wn) return;
    const int b = t / (hn * wn);
    const int yx = t % (hn * wn);
    const float* fp = feat + b * Cn * hn * wn + yx;
    float f[Cn];
#pragma unroll
    for (int c = 0; c < Cn; c++) f[c] = fp[c * hn * wn];
    float o0 = bs2[0], o1 = bs2[1], o2 = bs2[2];
#pragma unroll 1
    for (int co = 0; co < Cn; co += 4) {    // 4 accumulators for ILP
        float v0 = bs1[co], v1 = bs1[co + 1], v2 = bs1[co + 2], v3 = bs1[co + 3];
        const float* wr = ws1 + co * Cn;
#pragma unroll
        for (int ci = 0; ci < Cn; ci++) {
            const float fv = f[ci];
            v0 = fmaf(wr[ci], fv, v0);
            v1 = fmaf(wr[Cn + ci], fv, v1);
            v2 = fmaf(wr[2 * Cn + ci], fv, v2);
            v3 = fmaf(wr[3 * Cn + ci], fv, v3);
        }
        v0 = fmaxf(v0, 0.f); v1 = fmaxf(v1, 0.f); v2 = fmaxf(v2, 0.f); v3 = fmaxf(v3, 0.f);
#pragma unroll
        for (int u = 0; u < 4; u++) {
            const float vv = (u == 0) ? v0 : (u == 1) ? v1 : (u == 2) ? v2 : v3;
            o0 = fmaf(ws2[co + u], vv, o0);
            o1 = fmaf(ws2[Cn + co + u], vv, o1);
            o2 = fmaf(ws2[2 * Cn + co + u], vv, o2);
        }
    }
    sc[(b * 3 + 0) * hn * wn + yx] = o0;
    sc[(b * 3 + 1) * hn * wn + yx] = o1;
    sc[(b * 3 + 2) * hn * wn + yx] = o2;
}

// ---------------- fused main kernel ----------------
// Operand-swapped GEMMs: D = W (A-operand, global->VGPR stream) x Act^T
// (B-operand from LDS). C layout row=outch, col=pixel => epilogue writes 4
// consecutive channels at fixed pixel => packed ds_write_b64 into Abuf.
// NEXT_MODE: 0 = none, 1 = tail-prefetch next layer (4 frags/kstep),
//            2 = tail-prefetch next layer (1 frag/kstep, into buf[..][0]).
template <int KSTEPS, int NEXT_MODE>
__device__ __forceinline__ void gemm_sw(const bf16x8* __restrict__ wf,
                                        const bf16x8* __restrict__ wfn,
                                        __bf16 (&Abuf)[TM][SP],
                                        f32x4 (&acc)[4][4], bf16x8 (&buf)[2][4],
                                        int wv, int lane, int lane16, int quad)
{
    const int mb0 = wv * 4;
#pragma unroll
    for (int k0 = 0; k0 < KSTEPS; k0++) {
        bf16x8 aw[4];
#pragma unroll
        for (int j = 0; j < 4; j++) aw[j] = buf[k0 & 1][j];
        if (k0 + 2 < KSTEPS) {
#pragma unroll
            for (int j = 0; j < 4; j++)
                buf[k0 & 1][j] = wf[((k0 + 2) * 16 + mb0 + j) * 64 + lane];
        } else if (NEXT_MODE == 1) {
#pragma unroll
            for (int j = 0; j < 4; j++)
                buf[k0 & 1][j] = wfn[((k0 + 2 - KSTEPS) * 16 + mb0 + j) * 64 + lane];
        } else if (NEXT_MODE == 2) {
            buf[k0 & 1][0] = wfn[(k0 + 2 - KSTEPS) * 64 + lane];
        }
        bf16x8 gfr[4];
#pragma unroll
        for (int nb = 0; nb < 4; nb++)
            gfr[nb] = *(const bf16x8*)&Abuf[nb * 16 + lane16][k0 * 32 + quad * 8];
#pragma unroll
        for (int nb = 0; nb < 4; nb++)
#pragma unroll
            for (int j = 0; j < 4; j++)
                acc[nb][j] = __builtin_amdgcn_mfma_f32_16x16x32_bf16(aw[j], gfr[nb], acc[nb][j], 0, 0, 0);
    }
    if (NEXT_MODE == 1 && (KSTEPS & 1)) {   // fix buffer parity for next gemm
#pragma unroll
        for (int j = 0; j < 4; j++) {
            bf16x8 tmp = buf[0][j]; buf[0][j] = buf[1][j]; buf[1][j] = tmp;
        }
    }
}

__device__ __forceinline__ float gelu_fast(float x) {
    // tanh-form gelu via sigmoid in exp2 domain: x * 1/(1 + 2^(x*(d0+d1*x^2)))
    const float d0 = -2.302118074f;   // -2*0.7978845608*log2(e)
    const float d1 = -0.1029453754f;  // -2*0.0356774081*log2(e)
    float t = x * x;
    float a = x * fmaf(t, d1, d0);
    float e = __builtin_amdgcn_exp2f(a);
    return x * __builtin_amdgcn_rcpf(1.f + e);
}

__global__ __launch_bounds__(256, 3) void liif_main(
    const float* __restrict__ feat, const float* __restrict__ b1eff,
    const float* __restrict__ b2v, const __bf16* __restrict__ wb,
    const float* __restrict__ sc, float* __restrict__ out)
{
    __shared__ __align__(16) __bf16 Abuf[TM][SP];

    const int t = threadIdx.x;
    const int wv = t >> 6;
    const int lane = t & 63;
    const int lane16 = lane & 15;
    const int quad = lane >> 4;

    const int wg = blockIdx.x;
    constexpr int TPR = Wn / TM;  // 6 tiles per HR row
    const int tx = wg % TPR;
    const int Y = (wg / TPR) % Hn;
    const int b = wg / (TPR * Hn);
    const int X0 = tx * TM;

    const float cy = -1.f + 1.f / Hn + (2.f / Hn) * (float)Y;

    const bf16x8* wf1 = (const bf16x8*)wb;
    const bf16x8* wf2 = wf1 + L1_FRAGS;
    const bf16x8* w2f = wf1 + (L1_FRAGS + L2_FRAGS);

    // issue layer-1 initial weight prefetch BEFORE the gather (overlap latency)
    bf16x8 buf[2][4];
    {
        const int mb0 = wv * 4;
#pragma unroll
        for (int j = 0; j < 4; j++) buf[0][j] = wf1[(mb0 + j) * 64 + lane];
#pragma unroll
        for (int j = 0; j < 4; j++) buf[1][j] = wf1[(16 + mb0 + j) * 64 + lane];
    }

    // ---------- phase 1: build grid features [64 x 266] bf16 in Abuf ----------
    {
        const int p = lane;     // pixel in tile
        const int j = wv;       // this wave handles corner j's gather
        const int X = X0 + p;
        const float cx = -1.f + 1.f / Wn + (2.f / Wn) * (float)X;
        float rely[4], relx[4], area[4];
        int iyv[4], ixv[4];
#pragma unroll
        for (int c = 0; c < 4; c++) {
            const float vx = (c & 2) ? 1.f : -1.f;   // shift along height
            const float vy = (c & 1) ? 1.f : -1.f;   // shift along width
            float sy = fminf(fmaxf(cy + vx * (1.f / hn) + 1e-6f, -1.f + 1e-6f), 1.f - 1e-6f);
            float sx = fminf(fmaxf(cx + vy * (1.f / wn) + 1e-6f, -1.f + 1e-6f), 1.f - 1e-6f);
            float uy = ((sy + 1.f) * hn - 1.f) * 0.5f;
            float ux = ((sx + 1.f) * wn - 1.f) * 0.5f;
            int iy = min(max((int)rintf(uy), 0), hn - 1);   // round-half-even == jnp.round
            int ix = min(max((int)rintf(ux), 0), wn - 1);
            float oy = -1.f + 1.f / hn + (2.f / hn) * (float)iy;
            float ox = -1.f + 1.f / wn + (2.f / wn) * (float)ix;
            rely[c] = (cy - oy) * hn;
            relx[c] = (cx - ox) * wn;
            area[c] = fabsf(rely[c] * relx[c]) + 1e-9f;
            iyv[c] = iy; ixv[c] = ix;
        }
        const float tot = area[0] + area[1] + area[2] + area[3];
        const float wj = area[3 - j] / tot;   // LIIF area swap 0<->3, 1<->2

        if (j == 0) {  // channels 0..7: [rel_y0, rel_x0, ..., rel_y3, rel_x3]
            bf16x8 v;
#pragma unroll
            for (int c = 0; c < 4; c++) { v[2 * c] = (__bf16)rely[c]; v[2 * c + 1] = (__bf16)relx[c]; }
            *(bf16x8*)&Abuf[p][0] = v;
        }
        // channels 8+64j .. 8+64j+63: feat at (iy_j, ix_j) scaled by wj
        const float* fb = feat + ((b * Cn) * hn + iyv[j]) * wn + ixv[j];
#pragma unroll
        for (int c8 = 0; c8 < 8; c8++) {
            bf16x8 v;
#pragma unroll
            for (int cc = 0; cc < 8; cc++)
                v[cc] = (__bf16)(fb[(c8 * 8 + cc) * (hn * wn)] * wj);
            *(bf16x8*)&Abuf[p][8 + 64 * j + c8 * 8] = v;
        }
        if (j == 3) {  // channels 264..287 zero (rel_cell folded into b1eff)
            bf16x8 z;
#pragma unroll
            for (int cc = 0; cc < 8; cc++) z[cc] = (__bf16)0.f;
            *(bf16x8*)&Abuf[p][264] = z;
            *(bf16x8*)&Abuf[p][272] = z;
            *(bf16x8*)&Abuf[p][280] = z;
        }
    }
    __syncthreads();

    // ---------- layer 1: W00[256x288] x G^T -> X^T (acc row=outch, col=pixel) ----------
    f32x4 acc[4][4];
#pragma unroll
    for (int nb = 0; nb < 4; nb++)
#pragma unroll
        for (int j = 0; j < 4; j++) acc[nb][j] = (f32x4){0.f, 0.f, 0.f, 0.f};

    gemm_sw<9, 1>(wf1, wf2, Abuf, acc, buf, wv, lane, lane16, quad);

    __syncthreads();  // all B-frag (grid) readers done before overwriting Abuf with X
    // epilogue 1: no bias (b00 + rel_cell folded into b1eff); packed b64 writes
#pragma unroll
    for (int j = 0; j < 4; j++) {
        const int chb = (wv * 4 + j) * 16 + quad * 4;
#pragma unroll
        for (int nb = 0; nb < 4; nb++) {
            bf16x4 v;
#pragma unroll
            for (int r = 0; r < 4; r++) v[r] = (__bf16)acc[nb][j][r];
            *(bf16x4*)&Abuf[nb * 16 + lane16][chb] = v;
        }
    }
    __syncthreads();

    // ---------- layer 2: W1[256x256] x X -> Y^T, gelu epilogue ----------
#pragma unroll
    for (int nb = 0; nb < 4; nb++)
#pragma unroll
        for (int j = 0; j < 4; j++) acc[nb][j] = (f32x4){0.f, 0.f, 0.f, 0.f};

    gemm_sw<8, 2>(wf2, w2f, Abuf, acc, buf, wv, lane, lane16, quad);

    __syncthreads();
#pragma unroll
    for (int j = 0; j < 4; j++) {
        const int chb = (wv * 4 + j) * 16 + quad * 4;
        const f32x4 bias = *(const f32x4*)&b1eff[chb];
#pragma unroll
        for (int nb = 0; nb < 4; nb++) {
            bf16x4 v;
#pragma unroll
            for (int r = 0; r < 4; r++)
                v[r] = (__bf16)gelu_fast(acc[nb][j][r] + bias[r]);
            *(bf16x4*)&Abuf[nb * 16 + lane16][chb] = v;
        }
    }
    __syncthreads();

    // ---------- layer 3: W2[16x256] x Y -> out^T; wave wv owns pixel-block wv ----------
    f32x4 acc3 = (f32x4){0.f, 0.f, 0.f, 0.f};
#pragma unroll
    for (int k0 = 0; k0 < 8; k0++) {
        bf16x8 bw = buf[k0 & 1][0];
        if (k0 + 2 < 8) buf[k0 & 1][0] = w2f[(k0 + 2) * 64 + lane];
        bf16x8 yf = *(const bf16x8*)&Abuf[wv * 16 + lane16][k0 * 32 + quad * 8];
        acc3 = __builtin_amdgcn_mfma_f32_16x16x32_bf16(bw, yf, acc3, 0, 0, 0);
    }

    // ---------- epilogue: rows 0..2 (quad 0) hold the 3 output channels ----------
    if (quad == 0) {
        const int pix = wv * 16 + lane16;
        const int X = X0 + pix;
        const float uy = ((cy + 1.f) * hn - 1.f) * 0.5f;
        const float fy = floorf(uy);
        const float wy = uy - fy;
        const int y0i = min(max((int)fy, 0), hn - 1);
        const int y1i = min(max((int)fy + 1, 0), hn - 1);
        const float cx = -1.f + 1.f / Wn + (2.f / Wn) * (float)X;
        const float ux = ((cx + 1.f) * wn - 1.f) * 0.5f;
        const float fx = floorf(ux);
        const float wx = ux - fx;
        const int x0i = min(max((int)fx, 0), wn - 1);
        const int x1i = min(max((int)fx + 1, 0), wn - 1);
        const float w00b = (1.f - wy) * (1.f - wx), w01b = (1.f - wy) * wx;
        const float w10b = wy * (1.f - wx), w11b = wy * wx;
#pragma unroll
        for (int r = 0; r < 3; r++) {
            const float* scb = sc + (b * 3 + r) * (hn * wn);
            const float samp = scb[y0i * wn + x0i] * w00b + scb[y0i * wn + x1i] * w01b
                             + scb[y1i * wn + x0i] * w10b + scb[y1i * wn + x1i] * w11b;
            out[((b * 3 + r) * Hn + Y) * Wn + X] = acc3[r] + b2v[r] + samp;
        }
    }
}

extern "C" void kernel_launch(void* const* d_in, const int* in_sizes, int n_in,
                              void* d_out, int out_size, void* d_ws, size_t ws_size,
                              hipStream_t stream)
{
    const float* feat = (const float*)d_in[0];
    const float* w00  = (const float*)d_in[1];
    const float* b00  = (const float*)d_in[2];
    const float* w1   = (const float*)d_in[3];
    const float* b1   = (const float*)d_in[4];
    const float* w2   = (const float*)d_in[5];
    const float* b2   = (const float*)d_in[6];
    const float* ws1  = (const float*)d_in[7];
    const float* bs1  = (const float*)d_in[8];
    const float* ws2  = (const float*)d_in[9];
    const float* bs2  = (const float*)d_in[10];
    float* out = (float*)d_out;

    __bf16* wb    = (__bf16*)d_ws;
    float* scbuf  = (float*)((char*)d_ws + SC_OFF_BYTES);
    float* b1eff  = (float*)((char*)d_ws + B1EFF_OFF_BYTES);

    prep_weights<<<N_FRAGS / 256 + 1, 256, 0, stream>>>(w00, w1, w2, b00, b1, wb, b1eff);
    prep_sc<<<(Bn * hn * wn + 255) / 256, 256, 0, stream>>>(feat, ws1, bs1, ws2, bs2, scbuf);
    liif_main<<<Bn * Hn * (Wn / TM), 256, 0, stream>>>(feat, b1eff, b2, wb, scbuf, out);
}

// Round 4
// 211.134 us; speedup vs baseline: 1.6029x; 1.0042x over previous
//
#include <hip/hip_runtime.h>

typedef __bf16 bf16x8 __attribute__((ext_vector_type(8)));
typedef __bf16 bf16x4 __attribute__((ext_vector_type(4)));
typedef float f32x4 __attribute__((ext_vector_type(4)));

namespace {
constexpr int Bn = 2, Cn = 64, hn = 96, wn = 96, Hn = 384, Wn = 384;
constexpr int CIN = 266;
constexpr int TM = 64;                      // pixels per workgroup tile
constexpr int SP = 296;                     // Abuf row stride (bf16): 592B
// fragment-major weight layouts (built by prep_weights). A-frag mapping for
// mfma_f32_16x16x32_bf16: lane l supplies A[m = l&15][k = (l>>4)*8 + j].
constexpr int L1_FRAGS = 9 * 16 * 64;       // 9216
constexpr int L2_FRAGS = 8 * 16 * 64;       // 8192
constexpr int L3_FRAGS = 8 * 64;            // 512
constexpr int N_FRAGS = L1_FRAGS + L2_FRAGS + L3_FRAGS;   // 17920
constexpr int SC_OFF_BYTES = N_FRAGS * 16;                 // 286720
constexpr int B1EFF_OFF_BYTES = SC_OFF_BYTES + Bn * 3 * hn * wn * 4;
}

// ---------------- prep: weights fp32 -> bf16 fragment-major + b1eff ----------------
__global__ void prep_weights(const float* __restrict__ w00, const float* __restrict__ w1,
                             const float* __restrict__ w2, const float* __restrict__ b00,
                             const float* __restrict__ b1,
                             __bf16* __restrict__ wb, float* __restrict__ b1eff)
{
    if (blockIdx.x == N_FRAGS / 256) {
        // b1eff[o] = b1[o] + sum_c w1[o][c] * (b00[c] + 0.5*(w00[c][264]+w00[c][265]))
        __shared__ float cb[256];
        const int o = threadIdx.x;
        cb[o] = b00[o] + 0.5f * (w00[o * CIN + 264] + w00[o * CIN + 265]);
        __syncthreads();
        float v = b1[o];
#pragma unroll 4
        for (int k = 0; k < 256; k++) v = fmaf(w1[o * 256 + k], cb[k], v);
        b1eff[o] = v;
        return;
    }
    const int f = blockIdx.x * 256 + threadIdx.x;
    bf16x8 v;
    if (f < L1_FRAGS) {
        const int k0 = f >> 10;             // /(16*64)
        const int mb = (f >> 6) & 15;
        const int l  = f & 63;
        const int m  = mb * 16 + (l & 15);
        const int kb = k0 * 32 + (l >> 4) * 8;
#pragma unroll
        for (int j = 0; j < 8; j++)
            v[j] = (kb + j < CIN) ? (__bf16)w00[m * CIN + kb + j] : (__bf16)0.f;
    } else if (f < L1_FRAGS + L2_FRAGS) {
        const int g = f - L1_FRAGS;
        const int k0 = g >> 10;
        const int mb = (g >> 6) & 15;
        const int l  = g & 63;
        const int m  = mb * 16 + (l & 15);
        const int kb = k0 * 32 + (l >> 4) * 8;
#pragma unroll
        for (int j = 0; j < 8; j++) v[j] = (__bf16)w1[m * 256 + kb + j];
    } else {
        const int g = f - (L1_FRAGS + L2_FRAGS);
        const int k0 = g >> 6;
        const int l  = g & 63;
        const int m  = l & 15;
        const int kb = k0 * 32 + (l >> 4) * 8;
#pragma unroll
        for (int j = 0; j < 8; j++)
            v[j] = (m < 3) ? (__bf16)w2[m * 256 + kb + j] : (__bf16)0.f;
    }
    *(bf16x8*)(wb + f * 8) = v;
}

// ---------------- prep: shortcut MLP on LR grid (fp32) ----------------
__global__ void prep_sc(const float* __restrict__ feat, const float* __restrict__ ws1,
                        const float* __restrict__ bs1, const float* __restrict__ ws2,
                        const float* __restrict__ bs2, float* __restrict__ sc)
{
    const int t = blockIdx.x * 256 + threadIdx.x;
    if (t >= Bn * hn * wn) return;
    const int b = t / (hn * wn);
    const int yx = t % (hn * wn);
    const float* fp = feat + b * Cn * hn * wn + yx;
    float f[Cn];
#pragma unroll
    for (int c = 0; c < Cn; c++) f[c] = fp[c * hn * wn];
    float o0 = bs2[0], o1 = bs2[1], o2 = bs2[2];
#pragma unroll 1
    for (int co = 0; co < Cn; co += 4) {    // 4 accumulators for ILP
        float v0 = bs1[co], v1 = bs1[co + 1], v2 = bs1[co + 2], v3 = bs1[co + 3];
        const float* wr = ws1 + co * Cn;
#pragma unroll
        for (int ci = 0; ci < Cn; ci++) {
            const float fv = f[ci];
            v0 = fmaf(wr[ci], fv, v0);
            v1 = fmaf(wr[Cn + ci], fv, v1);
            v2 = fmaf(wr[2 * Cn + ci], fv, v2);
            v3 = fmaf(wr[3 * Cn + ci], fv, v3);
        }
        v0 = fmaxf(v0, 0.f); v1 = fmaxf(v1, 0.f); v2 = fmaxf(v2, 0.f); v3 = fmaxf(v3, 0.f);
#pragma unroll
        for (int u = 0; u < 4; u++) {
            const float vv = (u == 0) ? v0 : (u == 1) ? v1 : (u == 2) ? v2 : v3;
            o0 = fmaf(ws2[co + u], vv, o0);
            o1 = fmaf(ws2[Cn + co + u], vv, o1);
            o2 = fmaf(ws2[2 * Cn + co + u], vv, o2);
        }
    }
    sc[(b * 3 + 0) * hn * wn + yx] = o0;
    sc[(b * 3 + 1) * hn * wn + yx] = o1;
    sc[(b * 3 + 2) * hn * wn + yx] = o2;
}

// ---------------- fused main kernel ----------------
// Operand-swapped GEMMs: D = W (A-operand, global->VGPR stream) x Act^T
// (B-operand from LDS). Double-buffer = two NAMED arrays bE/bO with
// compile-time-only indexing (round-3 lesson: buf[k0&1] + runtime parity
// swap demoted the buffer to scratch -> 59 MB of HBM spill traffic).
// Precondition: E holds kstep0 frags, O holds kstep1 frags.
// NEXT_MODE 1: tail-prefetch next layer's ksteps 0,1 (4 frags each).
// NEXT_MODE 2: tail-prefetch next layer's ksteps 0,1 (slot 0 only).
template <int KSTEPS, int NEXT_MODE>
__device__ __forceinline__ void gemm_sw(const bf16x8* __restrict__ wf,
                                        const bf16x8* __restrict__ wfn,
                                        __bf16 (&Abuf)[TM][SP],
                                        f32x4 (&acc)[4][4],
                                        bf16x8 (&E)[4], bf16x8 (&O)[4],
                                        int wv, int lane, int lane16, int quad)
{
    const int mb0 = wv * 4;

    auto step = [&](int k0, bf16x8 (&bf)[4]) {
        bf16x8 aw[4];
#pragma unroll
        for (int j = 0; j < 4; j++) aw[j] = bf[j];
        const int kt = k0 + 2;
        if (kt < KSTEPS) {
#pragma unroll
            for (int j = 0; j < 4; j++)
                bf[j] = wf[(kt * 16 + mb0 + j) * 64 + lane];
        } else if (NEXT_MODE == 1) {
#pragma unroll
            for (int j = 0; j < 4; j++)
                bf[j] = wfn[((kt - KSTEPS) * 16 + mb0 + j) * 64 + lane];
        } else if (NEXT_MODE == 2) {
            bf[0] = wfn[(kt - KSTEPS) * 64 + lane];
        }
        bf16x8 gfr[4];
#pragma unroll
        for (int nb = 0; nb < 4; nb++)
            gfr[nb] = *(const bf16x8*)&Abuf[nb * 16 + lane16][k0 * 32 + quad * 8];
#pragma unroll
        for (int nb = 0; nb < 4; nb++)
#pragma unroll
            for (int j = 0; j < 4; j++)
                acc[nb][j] = __builtin_amdgcn_mfma_f32_16x16x32_bf16(aw[j], gfr[nb], acc[nb][j], 0, 0, 0);
    };

#pragma unroll
    for (int kk = 0; kk < KSTEPS / 2; kk++) {
        step(2 * kk, E);
        step(2 * kk + 1, O);
    }
    if (KSTEPS & 1) step(KSTEPS - 1, E);
}

__device__ __forceinline__ float gelu_fast(float x) {
    // tanh-form gelu via sigmoid in exp2 domain: x * 1/(1 + 2^(x*(d0+d1*x^2)))
    const float d0 = -2.302118074f;   // -2*0.7978845608*log2(e)
    const float d1 = -0.1029453754f;  // -2*0.0356774081*log2(e)
    float t = x * x;
    float a = x * fmaf(t, d1, d0);
    float e = __builtin_amdgcn_exp2f(a);
    return x * __builtin_amdgcn_rcpf(1.f + e);
}

__global__ __launch_bounds__(256, 3) void liif_main(
    const float* __restrict__ feat, const float* __restrict__ b1eff,
    const float* __restrict__ b2v, const __bf16* __restrict__ wb,
    const float* __restrict__ sc, float* __restrict__ out)
{
    __shared__ __align__(16) __bf16 Abuf[TM][SP];

    const int t = threadIdx.x;
    const int wv = t >> 6;
    const int lane = t & 63;
    const int lane16 = lane & 15;
    const int quad = lane >> 4;

    // XCD swizzle: hardware assigns XCD = blockIdx % 8 (round-robin). Remap so
    // each XCD owns a contiguous Y-band (96 HR rows -> 614 KB feat slice stays
    // L2-resident instead of all XCDs fetching all of feat).
    constexpr int NWG = Bn * Hn * (Wn / TM);       // 4608
    const int lt = (blockIdx.x & 7) * (NWG / 8) + (blockIdx.x >> 3);
    constexpr int TPR = Wn / TM;  // 6 tiles per HR row
    const int tx = lt % TPR;
    const int Y = (lt / TPR) % Hn;
    const int b = lt / (TPR * Hn);
    const int X0 = tx * TM;

    const float cy = -1.f + 1.f / Hn + (2.f / Hn) * (float)Y;

    const bf16x8* wf1 = (const bf16x8*)wb;
    const bf16x8* wf2 = wf1 + L1_FRAGS;
    const bf16x8* w2f = wf1 + (L1_FRAGS + L2_FRAGS);

    // issue layer-1 initial weight prefetch BEFORE the gather (overlap latency)
    bf16x8 bE[4], bO[4];
    {
        const int mb0 = wv * 4;
#pragma unroll
        for (int j = 0; j < 4; j++) bE[j] = wf1[(mb0 + j) * 64 + lane];
#pragma unroll
        for (int j = 0; j < 4; j++) bO[j] = wf1[(16 + mb0 + j) * 64 + lane];
    }

    // ---------- phase 1: build grid features [64 x 266] bf16 in Abuf ----------
    {
        const int p = lane;     // pixel in tile
        const int j = wv;       // this wave handles corner j's gather
        const int X = X0 + p;
        const float cx = -1.f + 1.f / Wn + (2.f / Wn) * (float)X;
        float rely[4], relx[4], area[4];
        int iyv[4], ixv[4];
#pragma unroll
        for (int c = 0; c < 4; c++) {
            const float vx = (c & 2) ? 1.f : -1.f;   // shift along height
            const float vy = (c & 1) ? 1.f : -1.f;   // shift along width
            float sy = fminf(fmaxf(cy + vx * (1.f / hn) + 1e-6f, -1.f + 1e-6f), 1.f - 1e-6f);
            float sx = fminf(fmaxf(cx + vy * (1.f / wn) + 1e-6f, -1.f + 1e-6f), 1.f - 1e-6f);
            float uy = ((sy + 1.f) * hn - 1.f) * 0.5f;
            float ux = ((sx + 1.f) * wn - 1.f) * 0.5f;
            int iy = min(max((int)rintf(uy), 0), hn - 1);   // round-half-even == jnp.round
            int ix = min(max((int)rintf(ux), 0), wn - 1);
            float oy = -1.f + 1.f / hn + (2.f / hn) * (float)iy;
            float ox = -1.f + 1.f / wn + (2.f / wn) * (float)ix;
            rely[c] = (cy - oy) * hn;
            relx[c] = (cx - ox) * wn;
            area[c] = fabsf(rely[c] * relx[c]) + 1e-9f;
            iyv[c] = iy; ixv[c] = ix;
        }
        const float tot = area[0] + area[1] + area[2] + area[3];
        const float wj = area[3 - j] / tot;   // LIIF area swap 0<->3, 1<->2

        if (j == 0) {  // channels 0..7: [rel_y0, rel_x0, ..., rel_y3, rel_x3]
            bf16x8 v;
#pragma unroll
            for (int c = 0; c < 4; c++) { v[2 * c] = (__bf16)rely[c]; v[2 * c + 1] = (__bf16)relx[c]; }
            *(bf16x8*)&Abuf[p][0] = v;
        }
        // channels 8+64j .. 8+64j+63: feat at (iy_j, ix_j) scaled by wj
        const float* fb = feat + ((b * Cn) * hn + iyv[j]) * wn + ixv[j];
#pragma unroll
        for (int c8 = 0; c8 < 8; c8++) {
            bf16x8 v;
#pragma unroll
            for (int cc = 0; cc < 8; cc++)
                v[cc] = (__bf16)(fb[(c8 * 8 + cc) * (hn * wn)] * wj);
            *(bf16x8*)&Abuf[p][8 + 64 * j + c8 * 8] = v;
        }
        if (j == 3) {  // channels 264..287 zero (rel_cell folded into b1eff)
            bf16x8 z;
#pragma unroll
            for (int cc = 0; cc < 8; cc++) z[cc] = (__bf16)0.f;
            *(bf16x8*)&Abuf[p][264] = z;
            *(bf16x8*)&Abuf[p][272] = z;
            *(bf16x8*)&Abuf[p][280] = z;
        }
    }
    __syncthreads();

    // ---------- layer 1: W00[256x288] x G^T -> X^T (acc row=outch, col=pixel) ----------
    f32x4 acc[4][4];
#pragma unroll
    for (int nb = 0; nb < 4; nb++)
#pragma unroll
        for (int j = 0; j < 4; j++) acc[nb][j] = (f32x4){0.f, 0.f, 0.f, 0.f};

    gemm_sw<9, 1>(wf1, wf2, Abuf, acc, bE, bO, wv, lane, lane16, quad);
    // KSTEPS=9 odd: tail prefetches left wfn kstep0 in bO, kstep1 in bE.

    __syncthreads();  // all B-frag (grid) readers done before overwriting Abuf with X
    // epilogue 1: no bias (b00 + rel_cell folded into b1eff); packed b64 writes
#pragma unroll
    for (int j = 0; j < 4; j++) {
        const int chb = (wv * 4 + j) * 16 + quad * 4;
#pragma unroll
        for (int nb = 0; nb < 4; nb++) {
            bf16x4 v;
#pragma unroll
            for (int r = 0; r < 4; r++) v[r] = (__bf16)acc[nb][j][r];
            *(bf16x4*)&Abuf[nb * 16 + lane16][chb] = v;
        }
    }
    __syncthreads();

    // ---------- layer 2: W1[256x256] x X -> Y^T, gelu epilogue ----------
#pragma unroll
    for (int nb = 0; nb < 4; nb++)
#pragma unroll
        for (int j = 0; j < 4; j++) acc[nb][j] = (f32x4){0.f, 0.f, 0.f, 0.f};

    // NOTE swapped bO/bE: wfn kstep0 lives in bO (see above).
    gemm_sw<8, 2>(wf2, w2f, Abuf, acc, bO, bE, wv, lane, lane16, quad);
    // Tail left w2f kstep0 in bO[0], kstep1 in bE[0].

    __syncthreads();
#pragma unroll
    for (int j = 0; j < 4; j++) {
        const int chb = (wv * 4 + j) * 16 + quad * 4;
        const f32x4 bias = *(const f32x4*)&b1eff[chb];
#pragma unroll
        for (int nb = 0; nb < 4; nb++) {
            bf16x4 v;
#pragma unroll
            for (int r = 0; r < 4; r++)
                v[r] = (__bf16)gelu_fast(acc[nb][j][r] + bias[r]);
            *(bf16x4*)&Abuf[nb * 16 + lane16][chb] = v;
        }
    }
    __syncthreads();

    // ---------- layer 3: W2[16x256] x Y -> out^T; wave wv owns pixel-block wv ----------
    f32x4 acc3 = (f32x4){0.f, 0.f, 0.f, 0.f};
#pragma unroll
    for (int kk = 0; kk < 4; kk++) {
        {   // even kstep 2kk: frags in bO[0]
            bf16x8 bw = bO[0];
            if (2 * kk + 2 < 8) bO[0] = w2f[(2 * kk + 2) * 64 + lane];
            bf16x8 yf = *(const bf16x8*)&Abuf[wv * 16 + lane16][(2 * kk) * 32 + quad * 8];
            acc3 = __builtin_amdgcn_mfma_f32_16x16x32_bf16(bw, yf, acc3, 0, 0, 0);
        }
        {   // odd kstep 2kk+1: frags in bE[0]
            bf16x8 bw = bE[0];
            if (2 * kk + 3 < 8) bE[0] = w2f[(2 * kk + 3) * 64 + lane];
            bf16x8 yf = *(const bf16x8*)&Abuf[wv * 16 + lane16][(2 * kk + 1) * 32 + quad * 8];
            acc3 = __builtin_amdgcn_mfma_f32_16x16x32_bf16(bw, yf, acc3, 0, 0, 0);
        }
    }

    // ---------- epilogue: rows 0..2 (quad 0) hold the 3 output channels ----------
    if (quad == 0) {
        const int pix = wv * 16 + lane16;
        const int X = X0 + pix;
        const float uy = ((cy + 1.f) * hn - 1.f) * 0.5f;
        const float fy = floorf(uy);
        const float wy = uy - fy;
        const int y0i = min(max((int)fy, 0), hn - 1);
        const int y1i = min(max((int)fy + 1, 0), hn - 1);
        const float cx = -1.f + 1.f / Wn + (2.f / Wn) * (float)X;
        const float ux = ((cx + 1.f) * wn - 1.f) * 0.5f;
        const float fx = floorf(ux);
        const float wx = ux - fx;
        const int x0i = min(max((int)fx, 0), wn - 1);
        const int x1i = min(max((int)fx + 1, 0), wn - 1);
        const float w00b = (1.f - wy) * (1.f - wx), w01b = (1.f - wy) * wx;
        const float w10b = wy * (1.f - wx), w11b = wy * wx;
#pragma unroll
        for (int r = 0; r < 3; r++) {
            const float* scb = sc + (b * 3 + r) * (hn * wn);
            const float samp = scb[y0i * wn + x0i] * w00b + scb[y0i * wn + x1i] * w01b
                             + scb[y1i * wn + x0i] * w10b + scb[y1i * wn + x1i] * w11b;
            out[((b * 3 + r) * Hn + Y) * Wn + X] = acc3[r] + b2v[r] + samp;
        }
    }
}

extern "C" void kernel_launch(void* const* d_in, const int* in_sizes, int n_in,
                              void* d_out, int out_size, void* d_ws, size_t ws_size,
                              hipStream_t stream)
{
    const float* feat = (const float*)d_in[0];
    const float* w00  = (const float*)d_in[1];
    const float* b00  = (const float*)d_in[2];
    const float* w1   = (const float*)d_in[3];
    const float* b1   = (const float*)d_in[4];
    const float* w2   = (const float*)d_in[5];
    const float* b2   = (const float*)d_in[6];
    const float* ws1  = (const float*)d_in[7];
    const float* bs1  = (const float*)d_in[8];
    const float* ws2  = (const float*)d_in[9];
    const float* bs2  = (const float*)d_in[10];
    float* out = (float*)d_out;

    __bf16* wb    = (__bf16*)d_ws;
    float* scbuf  = (float*)((char*)d_ws + SC_OFF_BYTES);
    float* b1eff  = (float*)((char*)d_ws + B1EFF_OFF_BYTES);

    prep_weights<<<N_FRAGS / 256 + 1, 256, 0, stream>>>(w00, w1, w2, b00, b1, wb, b1eff);
    prep_sc<<<(Bn * hn * wn + 255) / 256, 256, 0, stream>>>(feat, ws1, bs1, ws2, bs2, scbuf);
    liif_main<<<Bn * Hn * (Wn / TM), 256, 0, stream>>>(feat, b1eff, b2, wb, scbuf, out);
}

// Round 5
// 198.526 us; speedup vs baseline: 1.7047x; 1.0635x over previous
//
#include <hip/hip_runtime.h>

typedef __bf16 bf16x8 __attribute__((ext_vector_type(8)));
typedef __bf16 bf16x4 __attribute__((ext_vector_type(4)));
typedef float f32x4 __attribute__((ext_vector_type(4)));

namespace {
constexpr int Bn = 2, Cn = 64, hn = 96, wn = 96, Hn = 384, Wn = 384;
constexpr int CIN = 266;
constexpr int TM = 64;                      // pixels per workgroup tile
constexpr int SP = 296;                     // Abuf row stride (bf16): 592B
// fragment-major weight layouts. A-frag mapping for mfma_f32_16x16x32_bf16:
// lane l supplies A[m = l&15][k = (l>>4)*8 + j].
constexpr int L1_FRAGS = 9 * 16 * 64;       // 9216
constexpr int L2_FRAGS = 8 * 16 * 64;       // 8192
constexpr int L3_FRAGS = 8 * 64;            // 512
constexpr int N_FRAGS = L1_FRAGS + L2_FRAGS + L3_FRAGS;   // 17920
constexpr int SC_OFF_BYTES = N_FRAGS * 16;                 // 286720
constexpr int B1EFF_OFF_BYTES = SC_OFF_BYTES + Bn * 3 * hn * wn * 4;
constexpr int FRAG_BLOCKS = N_FRAGS / 256;  // 70
constexpr int SC_BLOCKS = (Bn * hn * wn) / 256;  // 72
}

// ---------------- prep (single dispatch): weight frags + b1eff + shortcut MLP ----------------
__global__ void prep_all(const float* __restrict__ w00, const float* __restrict__ w1,
                         const float* __restrict__ w2, const float* __restrict__ b00,
                         const float* __restrict__ b1,
                         const float* __restrict__ feat, const float* __restrict__ ws1,
                         const float* __restrict__ bs1, const float* __restrict__ ws2,
                         const float* __restrict__ bs2,
                         __bf16* __restrict__ wb, float* __restrict__ b1eff,
                         float* __restrict__ sc)
{
    const int bid = blockIdx.x;
    if (bid < FRAG_BLOCKS) {
        const int f = bid * 256 + threadIdx.x;
        bf16x8 v;
        if (f < L1_FRAGS) {
            const int k0 = f >> 10;
            const int mb = (f >> 6) & 15;
            const int l  = f & 63;
            const int m  = mb * 16 + (l & 15);
            const int kb = k0 * 32 + (l >> 4) * 8;
#pragma unroll
            for (int j = 0; j < 8; j++)
                v[j] = (kb + j < CIN) ? (__bf16)w00[m * CIN + kb + j] : (__bf16)0.f;
        } else if (f < L1_FRAGS + L2_FRAGS) {
            const int g = f - L1_FRAGS;
            const int k0 = g >> 10;
            const int mb = (g >> 6) & 15;
            const int l  = g & 63;
            const int m  = mb * 16 + (l & 15);
            const int kb = k0 * 32 + (l >> 4) * 8;
#pragma unroll
            for (int j = 0; j < 8; j++) v[j] = (__bf16)w1[m * 256 + kb + j];
        } else {
            const int g = f - (L1_FRAGS + L2_FRAGS);
            const int k0 = g >> 6;
            const int l  = g & 63;
            const int m  = l & 15;
            const int kb = k0 * 32 + (l >> 4) * 8;
#pragma unroll
            for (int j = 0; j < 8; j++)
                v[j] = (m < 3) ? (__bf16)w2[m * 256 + kb + j] : (__bf16)0.f;
        }
        *(bf16x8*)(wb + f * 8) = v;
        return;
    }
    if (bid == FRAG_BLOCKS) {
        // b1eff[o] = b1[o] + sum_c w1[o][c]*(b00[c] + 0.5*(w00[c][264]+w00[c][265]))
        __shared__ float cb[256];
        const int o = threadIdx.x;
        cb[o] = b00[o] + 0.5f * (w00[o * CIN + 264] + w00[o * CIN + 265]);
        __syncthreads();
        float v = b1[o];
#pragma unroll 4
        for (int k = 0; k < 256; k++) v = fmaf(w1[o * 256 + k], cb[k], v);
        b1eff[o] = v;
        return;
    }
    // shortcut MLP on LR grid
    const int t = (bid - FRAG_BLOCKS - 1) * 256 + threadIdx.x;
    if (t >= Bn * hn * wn) return;
    const int b = t / (hn * wn);
    const int yx = t % (hn * wn);
    const float* fp = feat + b * Cn * hn * wn + yx;
    float f[Cn];
#pragma unroll
    for (int c = 0; c < Cn; c++) f[c] = fp[c * hn * wn];
    float o0 = bs2[0], o1 = bs2[1], o2 = bs2[2];
#pragma unroll 1
    for (int co = 0; co < Cn; co += 4) {
        float v0 = bs1[co], v1 = bs1[co + 1], v2 = bs1[co + 2], v3 = bs1[co + 3];
        const float* wr = ws1 + co * Cn;
#pragma unroll
        for (int ci = 0; ci < Cn; ci++) {
            const float fv = f[ci];
            v0 = fmaf(wr[ci], fv, v0);
            v1 = fmaf(wr[Cn + ci], fv, v1);
            v2 = fmaf(wr[2 * Cn + ci], fv, v2);
            v3 = fmaf(wr[3 * Cn + ci], fv, v3);
        }
        v0 = fmaxf(v0, 0.f); v1 = fmaxf(v1, 0.f); v2 = fmaxf(v2, 0.f); v3 = fmaxf(v3, 0.f);
#pragma unroll
        for (int u = 0; u < 4; u++) {
            const float vv = (u == 0) ? v0 : (u == 1) ? v1 : (u == 2) ? v2 : v3;
            o0 = fmaf(ws2[co + u], vv, o0);
            o1 = fmaf(ws2[Cn + co + u], vv, o1);
            o2 = fmaf(ws2[2 * Cn + co + u], vv, o2);
        }
    }
    sc[(b * 3 + 0) * hn * wn + yx] = o0;
    sc[(b * 3 + 1) * hn * wn + yx] = o1;
    sc[(b * 3 + 2) * hn * wn + yx] = o2;
}

__device__ __forceinline__ float gelu_fast(float x) {
    // tanh-form gelu via sigmoid in exp2 domain: x * 1/(1 + 2^(x*(d0+d1*x^2)))
    const float d0 = -2.302118074f;   // -2*0.7978845608*log2(e)
    const float d1 = -0.1029453754f;  // -2*0.0356774081*log2(e)
    float t = x * x;
    float a = x * fmaf(t, d1, d0);
    float e = __builtin_amdgcn_exp2f(a);
    return x * __builtin_amdgcn_rcpf(1.f + e);
}

__device__ __forceinline__ bf16x4 pack4(f32x4 x) {
    bf16x4 v;
    v[0] = (__bf16)x[0]; v[1] = (__bf16)x[1]; v[2] = (__bf16)x[2]; v[3] = (__bf16)x[3];
    return v;
}

// ---------------- fused main kernel ----------------
// Operand-swapped GEMMs: D = W (A-operand, global->VGPR stream) x Act^T
// (B-operand from LDS). R3/R4 lesson: ANY array/lambda indirection on the
// weight double-buffer defeats mem2reg -> scratch-resident buffer -> ~40-60MB
// of HBM scratch traffic + per-kstep vmcnt serialization. So the hot path is
// fully scalarized: named bf16x8 scalars wE0..3 / wO0..3 (even/odd ksteps),
// named f32x4 accumulators, hand-unrolled macros, GSTEP-before-load ordering
// (WAR keeps the distance-2 prefetch behind the consuming MFMAs).

#define MF(A, B, C) __builtin_amdgcn_mfma_f32_16x16x32_bf16((A), (B), (C), 0, 0, 0)

// 16 MFMAs of one kstep: weights W0..W3 (mblocks mb0..mb0+3) x 4 pixel-blocks
#define GSTEP(k0, W0, W1, W2, W3) do {                                          \
    const bf16x8 g0 = *(const bf16x8*)&Abuf[     lane16][(k0) * 32 + quad * 8]; \
    const bf16x8 g1 = *(const bf16x8*)&Abuf[16 + lane16][(k0) * 32 + quad * 8]; \
    const bf16x8 g2 = *(const bf16x8*)&Abuf[32 + lane16][(k0) * 32 + quad * 8]; \
    const bf16x8 g3 = *(const bf16x8*)&Abuf[48 + lane16][(k0) * 32 + quad * 8]; \
    a00 = MF(W0, g0, a00); a01 = MF(W1, g0, a01); a02 = MF(W2, g0, a02); a03 = MF(W3, g0, a03); \
    a10 = MF(W0, g1, a10); a11 = MF(W1, g1, a11); a12 = MF(W2, g1, a12); a13 = MF(W3, g1, a13); \
    a20 = MF(W0, g2, a20); a21 = MF(W1, g2, a21); a22 = MF(W2, g2, a22); a23 = MF(W3, g2, a23); \
    a30 = MF(W0, g3, a30); a31 = MF(W1, g3, a31); a32 = MF(W2, g3, a32); a33 = MF(W3, g3, a33); \
} while (0)

#define LDW(W0, W1, W2, W3, src, kk) do {             \
    W0 = (src)[((kk) * 16 + mb0 + 0) * 64 + lane];    \
    W1 = (src)[((kk) * 16 + mb0 + 1) * 64 + lane];    \
    W2 = (src)[((kk) * 16 + mb0 + 2) * 64 + lane];    \
    W3 = (src)[((kk) * 16 + mb0 + 3) * 64 + lane];    \
} while (0)

#define ZACC4(n) a##n##0 = zf; a##n##1 = zf; a##n##2 = zf; a##n##3 = zf

__global__ __launch_bounds__(256, 3) void liif_main(
    const float* __restrict__ feat, const float* __restrict__ b1eff,
    const float* __restrict__ b2v, const __bf16* __restrict__ wb,
    const float* __restrict__ sc, float* __restrict__ out)
{
    __shared__ __align__(16) __bf16 Abuf[TM][SP];

    const int t = threadIdx.x;
    const int wv = t >> 6;
    const int lane = t & 63;
    const int lane16 = lane & 15;
    const int quad = lane >> 4;
    const int mb0 = wv * 4;

    // XCD swizzle: HW assigns XCD = blockIdx % 8; remap so each XCD owns a
    // contiguous Y-band (614 KB feat slice stays L2-resident). FETCH 26->10MB.
    constexpr int NWG = Bn * Hn * (Wn / TM);       // 4608
    const int lt = (blockIdx.x & 7) * (NWG / 8) + (blockIdx.x >> 3);
    constexpr int TPR = Wn / TM;  // 6 tiles per HR row
    const int tx = lt % TPR;
    const int Y = (lt / TPR) % Hn;
    const int b = lt / (TPR * Hn);
    const int X0 = tx * TM;

    const float cy = -1.f + 1.f / Hn + (2.f / Hn) * (float)Y;

    const bf16x8* wf1 = (const bf16x8*)wb;
    const bf16x8* wf2 = wf1 + L1_FRAGS;
    const bf16x8* w2f = wf1 + (L1_FRAGS + L2_FRAGS);

    // layer-1 initial prefetch (ksteps 0,1) issued BEFORE the gather
    bf16x8 wE0, wE1, wE2, wE3, wO0, wO1, wO2, wO3;
    LDW(wE0, wE1, wE2, wE3, wf1, 0);
    LDW(wO0, wO1, wO2, wO3, wf1, 1);

    // ---------- phase 1: build grid features [64 x 266] bf16 in Abuf ----------
    {
        const int p = lane;     // pixel in tile
        const int j = wv;       // this wave handles corner j's gather
        const int X = X0 + p;
        const float cx = -1.f + 1.f / Wn + (2.f / Wn) * (float)X;
        float rely[4], relx[4], area[4];
        int iyv[4], ixv[4];
#pragma unroll
        for (int c = 0; c < 4; c++) {
            const float vx = (c & 2) ? 1.f : -1.f;   // shift along height
            const float vy = (c & 1) ? 1.f : -1.f;   // shift along width
            float sy = fminf(fmaxf(cy + vx * (1.f / hn) + 1e-6f, -1.f + 1e-6f), 1.f - 1e-6f);
            float sx = fminf(fmaxf(cx + vy * (1.f / wn) + 1e-6f, -1.f + 1e-6f), 1.f - 1e-6f);
            float uy = ((sy + 1.f) * hn - 1.f) * 0.5f;
            float ux = ((sx + 1.f) * wn - 1.f) * 0.5f;
            int iy = min(max((int)rintf(uy), 0), hn - 1);   // round-half-even == jnp.round
            int ix = min(max((int)rintf(ux), 0), wn - 1);
            float oy = -1.f + 1.f / hn + (2.f / hn) * (float)iy;
            float ox = -1.f + 1.f / wn + (2.f / wn) * (float)ix;
            rely[c] = (cy - oy) * hn;
            relx[c] = (cx - ox) * wn;
            area[c] = fabsf(rely[c] * relx[c]) + 1e-9f;
            iyv[c] = iy; ixv[c] = ix;
        }
        const float tot = area[0] + area[1] + area[2] + area[3];
        const float wj = area[3 - j] / tot;   // LIIF area swap 0<->3, 1<->2

        if (j == 0) {  // channels 0..7: [rel_y0, rel_x0, ..., rel_y3, rel_x3]
            bf16x8 v;
#pragma unroll
            for (int c = 0; c < 4; c++) { v[2 * c] = (__bf16)rely[c]; v[2 * c + 1] = (__bf16)relx[c]; }
            *(bf16x8*)&Abuf[p][0] = v;
        }
        // channels 8+64j .. 8+64j+63: feat at (iy_j, ix_j) scaled by wj
        const float* fb = feat + ((b * Cn) * hn + iyv[j]) * wn + ixv[j];
#pragma unroll
        for (int c8 = 0; c8 < 8; c8++) {
            bf16x8 v;
#pragma unroll
            for (int cc = 0; cc < 8; cc++)
                v[cc] = (__bf16)(fb[(c8 * 8 + cc) * (hn * wn)] * wj);
            *(bf16x8*)&Abuf[p][8 + 64 * j + c8 * 8] = v;
        }
        if (j == 3) {  // channels 264..287 zero (rel_cell folded into b1eff)
            bf16x8 z;
#pragma unroll
            for (int cc = 0; cc < 8; cc++) z[cc] = (__bf16)0.f;
            *(bf16x8*)&Abuf[p][264] = z;
            *(bf16x8*)&Abuf[p][272] = z;
            *(bf16x8*)&Abuf[p][280] = z;
        }
    }
    __syncthreads();

    const f32x4 zf = (f32x4){0.f, 0.f, 0.f, 0.f};
    f32x4 a00, a01, a02, a03, a10, a11, a12, a13;
    f32x4 a20, a21, a22, a23, a30, a31, a32, a33;
    ZACC4(0); ZACC4(1); ZACC4(2); ZACC4(3);

    // ---------- layer 1: W00[256x288] x G^T, 9 ksteps ----------
    GSTEP(0, wE0, wE1, wE2, wE3); LDW(wE0, wE1, wE2, wE3, wf1, 2);
    GSTEP(1, wO0, wO1, wO2, wO3); LDW(wO0, wO1, wO2, wO3, wf1, 3);
    GSTEP(2, wE0, wE1, wE2, wE3); LDW(wE0, wE1, wE2, wE3, wf1, 4);
    GSTEP(3, wO0, wO1, wO2, wO3); LDW(wO0, wO1, wO2, wO3, wf1, 5);
    GSTEP(4, wE0, wE1, wE2, wE3); LDW(wE0, wE1, wE2, wE3, wf1, 6);
    GSTEP(5, wO0, wO1, wO2, wO3); LDW(wO0, wO1, wO2, wO3, wf1, 7);
    GSTEP(6, wE0, wE1, wE2, wE3); LDW(wE0, wE1, wE2, wE3, wf1, 8);
    GSTEP(7, wO0, wO1, wO2, wO3); LDW(wO0, wO1, wO2, wO3, wf2, 0);  // next layer k0
    GSTEP(8, wE0, wE1, wE2, wE3); LDW(wE0, wE1, wE2, wE3, wf2, 1);  // next layer k1

    __syncthreads();  // all grid readers done before overwriting Abuf with X
    // epilogue 1: no bias (b00 + rel_cell folded into b1eff); packed b64 writes
    {
        const int ch0 = mb0 * 16 + quad * 4;
        *(bf16x4*)&Abuf[     lane16][ch0     ] = pack4(a00);
        *(bf16x4*)&Abuf[16 + lane16][ch0     ] = pack4(a10);
        *(bf16x4*)&Abuf[32 + lane16][ch0     ] = pack4(a20);
        *(bf16x4*)&Abuf[48 + lane16][ch0     ] = pack4(a30);
        *(bf16x4*)&Abuf[     lane16][ch0 + 16] = pack4(a01);
        *(bf16x4*)&Abuf[16 + lane16][ch0 + 16] = pack4(a11);
        *(bf16x4*)&Abuf[32 + lane16][ch0 + 16] = pack4(a21);
        *(bf16x4*)&Abuf[48 + lane16][ch0 + 16] = pack4(a31);
        *(bf16x4*)&Abuf[     lane16][ch0 + 32] = pack4(a02);
        *(bf16x4*)&Abuf[16 + lane16][ch0 + 32] = pack4(a12);
        *(bf16x4*)&Abuf[32 + lane16][ch0 + 32] = pack4(a22);
        *(bf16x4*)&Abuf[48 + lane16][ch0 + 32] = pack4(a32);
        *(bf16x4*)&Abuf[     lane16][ch0 + 48] = pack4(a03);
        *(bf16x4*)&Abuf[16 + lane16][ch0 + 48] = pack4(a13);
        *(bf16x4*)&Abuf[32 + lane16][ch0 + 48] = pack4(a23);
        *(bf16x4*)&Abuf[48 + lane16][ch0 + 48] = pack4(a33);
    }
    __syncthreads();

    ZACC4(0); ZACC4(1); ZACC4(2); ZACC4(3);

    // ---------- layer 2: W1[256x256] x X, 8 ksteps (k0 in wO, k1 in wE) ----------
    GSTEP(0, wO0, wO1, wO2, wO3); LDW(wO0, wO1, wO2, wO3, wf2, 2);
    GSTEP(1, wE0, wE1, wE2, wE3); LDW(wE0, wE1, wE2, wE3, wf2, 3);
    GSTEP(2, wO0, wO1, wO2, wO3); LDW(wO0, wO1, wO2, wO3, wf2, 4);
    GSTEP(3, wE0, wE1, wE2, wE3); LDW(wE0, wE1, wE2, wE3, wf2, 5);
    GSTEP(4, wO0, wO1, wO2, wO3); LDW(wO0, wO1, wO2, wO3, wf2, 6);
    GSTEP(5, wE0, wE1, wE2, wE3); LDW(wE0, wE1, wE2, wE3, wf2, 7);
    GSTEP(6, wO0, wO1, wO2, wO3); wO0 = w2f[0 * 64 + lane];          // w2 k0
    GSTEP(7, wE0, wE1, wE2, wE3); wE0 = w2f[1 * 64 + lane];          // w2 k1

    __syncthreads();
    // epilogue 2: bias + gelu, packed b64 writes
    {
        const int ch0 = mb0 * 16 + quad * 4;
        const f32x4 bi0 = *(const f32x4*)&b1eff[ch0];
        const f32x4 bi1 = *(const f32x4*)&b1eff[ch0 + 16];
        const f32x4 bi2 = *(const f32x4*)&b1eff[ch0 + 32];
        const f32x4 bi3 = *(const f32x4*)&b1eff[ch0 + 48];
#define GEL4(x, bi) { bf16x4 v; v[0] = (__bf16)gelu_fast((x)[0] + (bi)[0]); \
        v[1] = (__bf16)gelu_fast((x)[1] + (bi)[1]); \
        v[2] = (__bf16)gelu_fast((x)[2] + (bi)[2]); \
        v[3] = (__bf16)gelu_fast((x)[3] + (bi)[3]); vv = v; }
        bf16x4 vv;
        GEL4(a00, bi0); *(bf16x4*)&Abuf[     lane16][ch0     ] = vv;
        GEL4(a10, bi0); *(bf16x4*)&Abuf[16 + lane16][ch0     ] = vv;
        GEL4(a20, bi0); *(bf16x4*)&Abuf[32 + lane16][ch0     ] = vv;
        GEL4(a30, bi0); *(bf16x4*)&Abuf[48 + lane16][ch0     ] = vv;
        GEL4(a01, bi1); *(bf16x4*)&Abuf[     lane16][ch0 + 16] = vv;
        GEL4(a11, bi1); *(bf16x4*)&Abuf[16 + lane16][ch0 + 16] = vv;
        GEL4(a21, bi1); *(bf16x4*)&Abuf[32 + lane16][ch0 + 16] = vv;
        GEL4(a31, bi1); *(bf16x4*)&Abuf[48 + lane16][ch0 + 16] = vv;
        GEL4(a02, bi2); *(bf16x4*)&Abuf[     lane16][ch0 + 32] = vv;
        GEL4(a12, bi2); *(bf16x4*)&Abuf[16 + lane16][ch0 + 32] = vv;
        GEL4(a22, bi2); *(bf16x4*)&Abuf[32 + lane16][ch0 + 32] = vv;
        GEL4(a32, bi2); *(bf16x4*)&Abuf[48 + lane16][ch0 + 32] = vv;
        GEL4(a03, bi3); *(bf16x4*)&Abuf[     lane16][ch0 + 48] = vv;
        GEL4(a13, bi3); *(bf16x4*)&Abuf[16 + lane16][ch0 + 48] = vv;
        GEL4(a23, bi3); *(bf16x4*)&Abuf[32 + lane16][ch0 + 48] = vv;
        GEL4(a33, bi3); *(bf16x4*)&Abuf[48 + lane16][ch0 + 48] = vv;
#undef GEL4
    }
    __syncthreads();

    // ---------- layer 3: W2[16x256] x Y, 8 ksteps; wave wv owns pixel-block wv ----------
    f32x4 acc3 = zf;
#define YF(k0) (*(const bf16x8*)&Abuf[wv * 16 + lane16][(k0) * 32 + quad * 8])
    acc3 = MF(wO0, YF(0), acc3); wO0 = w2f[2 * 64 + lane];
    acc3 = MF(wE0, YF(1), acc3); wE0 = w2f[3 * 64 + lane];
    acc3 = MF(wO0, YF(2), acc3); wO0 = w2f[4 * 64 + lane];
    acc3 = MF(wE0, YF(3), acc3); wE0 = w2f[5 * 64 + lane];
    acc3 = MF(wO0, YF(4), acc3); wO0 = w2f[6 * 64 + lane];
    acc3 = MF(wE0, YF(5), acc3); wE0 = w2f[7 * 64 + lane];
    acc3 = MF(wO0, YF(6), acc3);
    acc3 = MF(wE0, YF(7), acc3);
#undef YF

    // ---------- epilogue: rows 0..2 (quad 0) hold the 3 output channels ----------
    if (quad == 0) {
        const int pix = wv * 16 + lane16;
        const int X = X0 + pix;
        const float uy = ((cy + 1.f) * hn - 1.f) * 0.5f;
        const float fy = floorf(uy);
        const float wy = uy - fy;
        const int y0i = min(max((int)fy, 0), hn - 1);
        const int y1i = min(max((int)fy + 1, 0), hn - 1);
        const float cx = -1.f + 1.f / Wn + (2.f / Wn) * (float)X;
        const float ux = ((cx + 1.f) * wn - 1.f) * 0.5f;
        const float fx = floorf(ux);
        const float wx = ux - fx;
        const int x0i = min(max((int)fx, 0), wn - 1);
        const int x1i = min(max((int)fx + 1, 0), wn - 1);
        const float w00b = (1.f - wy) * (1.f - wx), w01b = (1.f - wy) * wx;
        const float w10b = wy * (1.f - wx), w11b = wy * wx;
#pragma unroll
        for (int r = 0; r < 3; r++) {
            const float* scb = sc + (b * 3 + r) * (hn * wn);
            const float samp = scb[y0i * wn + x0i] * w00b + scb[y0i * wn + x1i] * w01b
                             + scb[y1i * wn + x0i] * w10b + scb[y1i * wn + x1i] * w11b;
            out[((b * 3 + r) * Hn + Y) * Wn + X] = acc3[r] + b2v[r] + samp;
        }
    }
}

extern "C" void kernel_launch(void* const* d_in, const int* in_sizes, int n_in,
                              void* d_out, int out_size, void* d_ws, size_t ws_size,
                              hipStream_t stream)
{
    const float* feat = (const float*)d_in[0];
    const float* w00  = (const float*)d_in[1];
    const float* b00  = (const float*)d_in[2];
    const float* w1   = (const float*)d_in[3];
    const float* b1   = (const float*)d_in[4];
    const float* w2   = (const float*)d_in[5];
    const float* b2   = (const float*)d_in[6];
    const float* ws1  = (const float*)d_in[7];
    const float* bs1  = (const float*)d_in[8];
    const float* ws2  = (const float*)d_in[9];
    const float* bs2  = (const float*)d_in[10];
    float* out = (float*)d_out;

    __bf16* wb    = (__bf16*)d_ws;
    float* scbuf  = (float*)((char*)d_ws + SC_OFF_BYTES);
    float* b1eff  = (float*)((char*)d_ws + B1EFF_OFF_BYTES);

    prep_all<<<FRAG_BLOCKS + 1 + SC_BLOCKS, 256, 0, stream>>>(
        w00, w1, w2, b00, b1, feat, ws1, bs1, ws2, bs2, wb, b1eff, scbuf);
    liif_main<<<Bn * Hn * (Wn / TM), 256, 0, stream>>>(feat, b1eff, b2, wb, scbuf, out);
}